// Round 5
// baseline (10510.286 us; speedup 1.0000x reference)
//
#include <hip/hip_runtime.h>
#include <hip/hip_fp16.h>

// GridPull: trilinear interpolation, dct2 reflect boundary, extrapolate=True.
// x: (1, 2, 192, 192, 192) f32; grid: (1, 192, 192, 192, 3) f32 -> (1, 2, 192^3) f32.
//
// R5 (= R4 + compile fix): bucketed gather for L2 locality.
//   1) repack x -> fp16 channel-interleaved 4x2x2 bricks (28.3 MB), as R3.
//   2) scatter: bin samples into 8 x-slab buckets (24 x-planes each) as 16B
//      records, wave-aggregated atomic cursors.
//   3) process: blockIdx%8 -> bucket, exploiting round-robin block->XCD
//      dispatch so each XCD gathers from a ~4.1 MB slab resident in its L2.
// Fabric-miss bytes: ~908 MB -> ~(85 grid + 126 rec_w + 126 rec_r + ~100 gather).

constexpr int DIM = 192;
constexpr int N = DIM * DIM * DIM;           // 7,077,888 (divisible by 256)

// brick geometry: 4(x) x 2(y) x 2(z) voxels * half2 = 64 B line
constexpr int NBX = DIM / 4, NBY = DIM / 2, NBZ = DIM / 2;
constexpr int NBRICKS = NBX * NBY * NBZ;
constexpr int XSTRIDE = NBY * NBZ * 16;      // half2 units per +4 in ix
constexpr int YSTRIDE = NBZ * 16;            // per +2 in iy
constexpr int ZSTRIDE = 16;                  // per +2 in iz

constexpr int NBUCKET = 8;                   // x-slabs of 24 planes (6 brick-planes)
constexpr int CAP = 983040;                  // records per bucket (256*3840); max bucket ~944K
constexpr int BLOCKS_PER_BUCKET = CAP / 256; // 3840

constexpr size_t BRICK_BYTES = (size_t)NBRICKS * 64;       // 28,311,552
constexpr size_t REC_BYTES   = (size_t)NBUCKET * CAP * 16; // 125,829,120
constexpr size_t CUR_OFFSET  = BRICK_BYTES + REC_BYTES;
constexpr size_t WS_NEED_FULL = CUR_OFFSET + 64;

// nontemporal-legal 16B vector type (HIP's uint4 is a class -> rejected)
typedef unsigned int uint4v __attribute__((ext_vector_type(4)));

__device__ __forceinline__ int reflect_dct2(int i, int n) {
    const int p = 2 * n;
    i = ((i % p) + p) % p;
    return (i >= n) ? (p - 1 - i) : i;
}

__device__ __forceinline__ int xterm(int ix) { return (ix >> 2) * XSTRIDE + ((ix & 3) << 2); }
__device__ __forceinline__ int yterm(int iy) { return (iy >> 1) * YSTRIDE + ((iy & 1) << 1); }
__device__ __forceinline__ int zterm(int iz) { return (iz >> 1) * ZSTRIDE + (iz & 1); }

// ---------- pass 1: fp16 brick repack ----------
__global__ __launch_bounds__(256) void repack_brick_kernel(
        const float* __restrict__ x, uint32_t* __restrict__ xb) {
    const int b = blockIdx.x * blockDim.x + threadIdx.x;
    if (b >= NBRICKS) return;
    const int bz = b % NBZ;
    const int t  = b / NBZ;
    const int by = t % NBY;
    const int bx = t / NBY;
    const int ix0 = bx * 4, iy0 = by * 2, iz0 = bz * 2;

    uint32_t vals[16];
#pragma unroll
    for (int s = 0; s < 16; ++s) {
        const int ix = ix0 + (s >> 2);
        const int iy = iy0 + ((s >> 1) & 1);
        const int iz = iz0 + (s & 1);
        const int n = (ix * DIM + iy) * DIM + iz;
        const __half2 h = __floats2half2_rn(x[n], x[N + n]);
        vals[s] = __builtin_bit_cast(uint32_t, h);
    }
    uint4v* dst = (uint4v*)(xb + (size_t)b * 16);
#pragma unroll
    for (int q = 0; q < 4; ++q) {
        uint4v v = { vals[4 * q + 0], vals[4 * q + 1], vals[4 * q + 2], vals[4 * q + 3] };
        dst[q] = v;
    }
}

// ---------- pass 2: bin samples into x-slab buckets ----------
__global__ __launch_bounds__(256) void scatter_kernel(
        const float* __restrict__ grid,
        uint4v* __restrict__ recs,
        int* __restrict__ cursors) {
    const int n = blockIdx.x * 256 + threadIdx.x;   // N % 256 == 0, no tail

    const float gx = __builtin_nontemporal_load(&grid[3 * n + 0]);
    const float gy = __builtin_nontemporal_load(&grid[3 * n + 1]);
    const float gz = __builtin_nontemporal_load(&grid[3 * n + 2]);

    const float fx = floorf(gx), fy = floorf(gy), fz = floorf(gz);
    const int lx = (int)fx, ly = (int)fy, lz = (int)fz;
    const float tx = gx - fx, ty = gy - fy, tz = gz - fz;

    const int ix0 = reflect_dct2(lx,     DIM);
    const int ix1 = reflect_dct2(lx + 1, DIM);
    const int iy0 = reflect_dct2(ly,     DIM);
    const int iy1 = reflect_dct2(ly + 1, DIM);
    const int iz0 = reflect_dct2(lz,     DIM);
    const int iz1 = reflect_dct2(lz + 1, DIM);

    const int b = ix0 / 24;                          // bucket = x-slab of 24 planes

    const uint32_t u1 = (uint32_t)ix0 | ((uint32_t)iy0 << 8) | ((uint32_t)iz0 << 16)
                      | ((uint32_t)(ix1 - ix0 + 1) << 24)
                      | ((uint32_t)(iy1 - iy0 + 1) << 26)
                      | ((uint32_t)(iz1 - iz0 + 1) << 28);
    const uint32_t txq = (uint32_t)(tx * 65536.0f);
    const uint32_t tyq = (uint32_t)(ty * 65536.0f);
    const uint32_t tzq = (uint32_t)(tz * 65536.0f);
    const uint4v rec = { (uint32_t)n, u1, txq | (tyq << 16), tzq };

    const int lane = threadIdx.x & 63;
#pragma unroll
    for (int k = 0; k < NBUCKET; ++k) {
        const unsigned long long m = __ballot(b == k);
        if (m) {
            const int leader = __ffsll((long long)m) - 1;
            const int cnt = __popcll(m);
            int base = 0;
            if (lane == leader) base = atomicAdd(&cursors[k], cnt);
            base = __shfl(base, leader);
            if (b == k) {
                const int rank = __popcll(m & ((1ull << lane) - 1ull));
                const int pos = base + rank;
                if (pos < CAP) {
                    __builtin_nontemporal_store(rec, &recs[(size_t)k * CAP + pos]);
                }
            }
        }
    }
}

// ---------- pass 3: process buckets (XCD-affine via blockIdx%8) ----------
__global__ __launch_bounds__(256) void process_kernel(
        const uint32_t* __restrict__ xb,
        const uint4v* __restrict__ recs,
        const int* __restrict__ cursors,
        float* __restrict__ out) {
    const int region = blockIdx.x & 7;               // round-robin -> XCD affinity
    const int chunk  = blockIdx.x >> 3;
    const int idx = chunk * 256 + threadIdx.x;
    int cnt = cursors[region];
    cnt = (cnt < CAP) ? cnt : CAP;
    if (idx >= cnt) return;

    const uint4v r = __builtin_nontemporal_load(&recs[(size_t)region * CAP + idx]);
    const int n = (int)r.x;
    const int ix0 = r.y & 255, iy0 = (r.y >> 8) & 255, iz0 = (r.y >> 16) & 255;
    const int ix1 = ix0 + (int)((r.y >> 24) & 3) - 1;
    const int iy1 = iy0 + (int)((r.y >> 26) & 3) - 1;
    const int iz1 = iz0 + (int)((r.y >> 28) & 3) - 1;
    const float tx = (float)(r.z & 65535u) * (1.0f / 65536.0f);
    const float ty = (float)(r.z >> 16)    * (1.0f / 65536.0f);
    const float tz = (float)(r.w & 65535u) * (1.0f / 65536.0f);

    const int tx0 = xterm(ix0), tx1 = xterm(ix1);
    const int ty0 = yterm(iy0), ty1 = yterm(iy1);
    const int tz0 = zterm(iz0), tz1 = zterm(iz1);

    const uint32_t u000 = xb[tx0 + ty0 + tz0];
    const uint32_t u001 = xb[tx0 + ty0 + tz1];
    const uint32_t u010 = xb[tx0 + ty1 + tz0];
    const uint32_t u011 = xb[tx0 + ty1 + tz1];
    const uint32_t u100 = xb[tx1 + ty0 + tz0];
    const uint32_t u101 = xb[tx1 + ty0 + tz1];
    const uint32_t u110 = xb[tx1 + ty1 + tz0];
    const uint32_t u111 = xb[tx1 + ty1 + tz1];

    const float wx0 = 1.0f - tx, wx1 = tx;
    const float wy0 = 1.0f - ty, wy1 = ty;
    const float wz0 = 1.0f - tz, wz1 = tz;

    const float w000 = wx0 * wy0 * wz0, w001 = wx0 * wy0 * wz1;
    const float w010 = wx0 * wy1 * wz0, w011 = wx0 * wy1 * wz1;
    const float w100 = wx1 * wy0 * wz0, w101 = wx1 * wy0 * wz1;
    const float w110 = wx1 * wy1 * wz0, w111 = wx1 * wy1 * wz1;

    const float2 f000 = __half22float2(__builtin_bit_cast(__half2, u000));
    const float2 f001 = __half22float2(__builtin_bit_cast(__half2, u001));
    const float2 f010 = __half22float2(__builtin_bit_cast(__half2, u010));
    const float2 f011 = __half22float2(__builtin_bit_cast(__half2, u011));
    const float2 f100 = __half22float2(__builtin_bit_cast(__half2, u100));
    const float2 f101 = __half22float2(__builtin_bit_cast(__half2, u101));
    const float2 f110 = __half22float2(__builtin_bit_cast(__half2, u110));
    const float2 f111 = __half22float2(__builtin_bit_cast(__half2, u111));

    const float acc0 = f000.x * w000 + f001.x * w001 + f010.x * w010 + f011.x * w011
                     + f100.x * w100 + f101.x * w101 + f110.x * w110 + f111.x * w111;
    const float acc1 = f000.y * w000 + f001.y * w001 + f010.y * w010 + f011.y * w011
                     + f100.y * w100 + f101.y * w101 + f110.y * w110 + f111.y * w111;

    out[n]     = acc0;
    out[N + n] = acc1;
}

// ---------- fallback: R3 monolithic brick gather ----------
__global__ __launch_bounds__(256) void grid_pull_brick_kernel(
        const uint32_t* __restrict__ xb,
        const float* __restrict__ grid,
        float* __restrict__ out) {
    const int n = blockIdx.x * blockDim.x + threadIdx.x;
    if (n >= N) return;

    const float gx = __builtin_nontemporal_load(&grid[3 * n + 0]);
    const float gy = __builtin_nontemporal_load(&grid[3 * n + 1]);
    const float gz = __builtin_nontemporal_load(&grid[3 * n + 2]);

    const float fx = floorf(gx), fy = floorf(gy), fz = floorf(gz);
    const int lx = (int)fx, ly = (int)fy, lz = (int)fz;
    const float tx = gx - fx, ty = gy - fy, tz = gz - fz;

    const int ix0 = reflect_dct2(lx,     DIM);
    const int ix1 = reflect_dct2(lx + 1, DIM);
    const int iy0 = reflect_dct2(ly,     DIM);
    const int iy1 = reflect_dct2(ly + 1, DIM);
    const int iz0 = reflect_dct2(lz,     DIM);
    const int iz1 = reflect_dct2(lz + 1, DIM);

    const int tx0 = xterm(ix0), tx1 = xterm(ix1);
    const int ty0 = yterm(iy0), ty1 = yterm(iy1);
    const int tz0 = zterm(iz0), tz1 = zterm(iz1);

    const uint32_t u000 = xb[tx0 + ty0 + tz0];
    const uint32_t u001 = xb[tx0 + ty0 + tz1];
    const uint32_t u010 = xb[tx0 + ty1 + tz0];
    const uint32_t u011 = xb[tx0 + ty1 + tz1];
    const uint32_t u100 = xb[tx1 + ty0 + tz0];
    const uint32_t u101 = xb[tx1 + ty0 + tz1];
    const uint32_t u110 = xb[tx1 + ty1 + tz0];
    const uint32_t u111 = xb[tx1 + ty1 + tz1];

    const float wx0 = 1.0f - tx, wx1 = tx;
    const float wy0 = 1.0f - ty, wy1 = ty;
    const float wz0 = 1.0f - tz, wz1 = tz;

    const float w000 = wx0 * wy0 * wz0, w001 = wx0 * wy0 * wz1;
    const float w010 = wx0 * wy1 * wz0, w011 = wx0 * wy1 * wz1;
    const float w100 = wx1 * wy0 * wz0, w101 = wx1 * wy0 * wz1;
    const float w110 = wx1 * wy1 * wz0, w111 = wx1 * wy1 * wz1;

    const float2 f000 = __half22float2(__builtin_bit_cast(__half2, u000));
    const float2 f001 = __half22float2(__builtin_bit_cast(__half2, u001));
    const float2 f010 = __half22float2(__builtin_bit_cast(__half2, u010));
    const float2 f011 = __half22float2(__builtin_bit_cast(__half2, u011));
    const float2 f100 = __half22float2(__builtin_bit_cast(__half2, u100));
    const float2 f101 = __half22float2(__builtin_bit_cast(__half2, u101));
    const float2 f110 = __half22float2(__builtin_bit_cast(__half2, u110));
    const float2 f111 = __half22float2(__builtin_bit_cast(__half2, u111));

    const float acc0 = f000.x * w000 + f001.x * w001 + f010.x * w010 + f011.x * w011
                     + f100.x * w100 + f101.x * w101 + f110.x * w110 + f111.x * w111;
    const float acc1 = f000.y * w000 + f001.y * w001 + f010.y * w010 + f011.y * w011
                     + f100.y * w100 + f101.y * w101 + f110.y * w110 + f111.y * w111;

    __builtin_nontemporal_store(acc0, &out[n]);
    __builtin_nontemporal_store(acc1, &out[N + n]);
}

extern "C" void kernel_launch(void* const* d_in, const int* in_sizes, int n_in,
                              void* d_out, int out_size, void* d_ws, size_t ws_size,
                              hipStream_t stream) {
    const float* x    = (const float*)d_in[0];
    const float* grid = (const float*)d_in[1];
    float* out        = (float*)d_out;

    const int threads = 256;
    const int rblocks = (NBRICKS + threads - 1) / threads;
    const int gblocks = N / threads;                 // exact

    if (ws_size >= WS_NEED_FULL) {
        uint32_t* xb   = (uint32_t*)d_ws;
        uint4v* recs   = (uint4v*)((char*)d_ws + BRICK_BYTES);
        int* cursors   = (int*)((char*)d_ws + CUR_OFFSET);

        (void)hipMemsetAsync(cursors, 0, NBUCKET * sizeof(int), stream);
        repack_brick_kernel<<<rblocks, threads, 0, stream>>>(x, xb);
        scatter_kernel<<<gblocks, threads, 0, stream>>>(grid, recs, cursors);
        process_kernel<<<NBUCKET * BLOCKS_PER_BUCKET, threads, 0, stream>>>(xb, recs, cursors, out);
    } else {
        // fallback: R3 path (needs 28.3 MB)
        uint32_t* xb = (uint32_t*)d_ws;
        repack_brick_kernel<<<rblocks, threads, 0, stream>>>(x, xb);
        grid_pull_brick_kernel<<<gblocks, threads, 0, stream>>>(xb, grid, out);
    }
}

// Round 6
// 620.422 us; speedup vs baseline: 16.9405x; 16.9405x over previous
//
#include <hip/hip_runtime.h>
#include <hip/hip_fp16.h>

// GridPull: trilinear interpolation, dct2 reflect boundary, extrapolate=True.
// x: (1, 2, 192, 192, 192) f32; grid: (1, 192, 192, 192, 3) f32 -> (1, 2, 192^3) f32.
//
// R6: atomic-free bucketed gather (count -> scan -> scatter -> process).
//   R5's global-atomic cursors (8 counters in one line) serialized the whole
//   device (10 ms). Replace with radix-partition: per-block histograms, one
//   tiny exclusive scan, then scatter with per-block LDS cursors only.
//   process uses blockIdx%8 -> XCD round-robin so each XCD gathers from a
//   ~3.8 MB x-slab resident in its 4 MB L2.

constexpr int DIM = 192;
constexpr int N = DIM * DIM * DIM;           // 7,077,888

// brick geometry: 4(x) x 2(y) x 2(z) voxels * half2 = one 64 B line
constexpr int NBX = DIM / 4, NBY = DIM / 2, NBZ = DIM / 2;
constexpr int NBRICKS = NBX * NBY * NBZ;
constexpr int XSTRIDE = NBY * NBZ * 16;      // half2 units per +4 in ix
constexpr int YSTRIDE = NBZ * 16;            // per +2 in iy
constexpr int ZSTRIDE = 16;                  // per +2 in iz

constexpr int NBUCKET = 8;                   // x-slabs of 24 planes
constexpr int NSCB = 512;                    // count/scatter blocks
constexpr int SPB  = N / NSCB;               // 13824 samples per block
constexpr int ITER = SPB / 256;              // 54
constexpr int HIST_N = NBUCKET * NSCB;       // 4096
constexpr int PB_BLOCKS = 3840;              // process blocks per bucket (covers 983040 >= max bucket ~944K)

constexpr size_t BRICK_BYTES = (size_t)NBRICKS * 64;   // 28,311,552
constexpr size_t REC_BYTES   = (size_t)N * 16;         // 113,246,208 (packed, exact)
constexpr size_t HIST_OFF    = BRICK_BYTES + REC_BYTES;
constexpr size_t OFFS_OFF    = HIST_OFF + (size_t)HIST_N * 4;
constexpr size_t BASE_OFF    = OFFS_OFF + (size_t)HIST_N * 4;
constexpr size_t WS_NEED     = BASE_OFF + 64;          // ~141.6 MB

// nontemporal-legal 16B vector type (HIP's uint4 is a class -> rejected)
typedef unsigned int uint4v __attribute__((ext_vector_type(4)));

__device__ __forceinline__ int reflect_dct2(int i, int n) {
    const int p = 2 * n;
    i = ((i % p) + p) % p;
    return (i >= n) ? (p - 1 - i) : i;
}

__device__ __forceinline__ int xterm(int ix) { return (ix >> 2) * XSTRIDE + ((ix & 3) << 2); }
__device__ __forceinline__ int yterm(int iy) { return (iy >> 1) * YSTRIDE + ((iy & 1) << 1); }
__device__ __forceinline__ int zterm(int iz) { return (iz >> 1) * ZSTRIDE + (iz & 1); }

// ---------- pass 1: fp16 brick repack ----------
__global__ __launch_bounds__(256) void repack_brick_kernel(
        const float* __restrict__ x, uint32_t* __restrict__ xb) {
    const int b = blockIdx.x * blockDim.x + threadIdx.x;
    if (b >= NBRICKS) return;
    const int bz = b % NBZ;
    const int t  = b / NBZ;
    const int by = t % NBY;
    const int bx = t / NBY;
    const int ix0 = bx * 4, iy0 = by * 2, iz0 = bz * 2;

    uint32_t vals[16];
#pragma unroll
    for (int s = 0; s < 16; ++s) {
        const int ix = ix0 + (s >> 2);
        const int iy = iy0 + ((s >> 1) & 1);
        const int iz = iz0 + (s & 1);
        const int n = (ix * DIM + iy) * DIM + iz;
        const __half2 h = __floats2half2_rn(x[n], x[N + n]);
        vals[s] = __builtin_bit_cast(uint32_t, h);
    }
    uint4v* dst = (uint4v*)(xb + (size_t)b * 16);
#pragma unroll
    for (int q = 0; q < 4; ++q) {
        uint4v v = { vals[4 * q + 0], vals[4 * q + 1], vals[4 * q + 2], vals[4 * q + 3] };
        dst[q] = v;
    }
}

// ---------- pass 2a: per-block bucket histograms (no global atomics) ----------
__global__ __launch_bounds__(256) void count_kernel(
        const float* __restrict__ grid, int* __restrict__ hist) {
    __shared__ int lh[NBUCKET];
    if (threadIdx.x < NBUCKET) lh[threadIdx.x] = 0;
    __syncthreads();

    int acc[NBUCKET];
#pragma unroll
    for (int k = 0; k < NBUCKET; ++k) acc[k] = 0;

    const int base = blockIdx.x * SPB;
    for (int s = 0; s < ITER; ++s) {
        const int n = base + s * 256 + threadIdx.x;
        const float gx = __builtin_nontemporal_load(&grid[3 * n]);
        const int ix0 = reflect_dct2((int)floorf(gx), DIM);
        const int b = ix0 / 24;
#pragma unroll
        for (int k = 0; k < NBUCKET; ++k) {
            const unsigned long long m = __ballot(b == k);
            acc[k] += __popcll(m);          // wave-uniform
        }
    }
    const int lane = threadIdx.x & 63;
#pragma unroll
    for (int k = 0; k < NBUCKET; ++k)
        if (lane == k) atomicAdd(&lh[k], acc[k]);   // LDS, 8 per wave total
    __syncthreads();
    if (threadIdx.x < NBUCKET)
        hist[threadIdx.x * NSCB + blockIdx.x] = lh[threadIdx.x];
}

// ---------- pass 2b: exclusive scan of 4096 hist entries (1 block) ----------
__global__ __launch_bounds__(256) void scan_kernel(
        const int* __restrict__ hist, int* __restrict__ offs, int* __restrict__ bases) {
    __shared__ int ls[256];
    const int t = threadIdx.x;
    int local[16];
    int sum = 0;
#pragma unroll
    for (int i = 0; i < 16; ++i) { local[i] = hist[t * 16 + i]; sum += local[i]; }
    ls[t] = sum;
    __syncthreads();
    for (int off = 1; off < 256; off <<= 1) {
        int v = 0;
        if (t >= off) v = ls[t - off];
        __syncthreads();
        ls[t] += v;
        __syncthreads();
    }
    const int ex = ls[t] - sum;              // exclusive prefix at flat index 16*t
    int run = ex;
#pragma unroll
    for (int i = 0; i < 16; ++i) { offs[t * 16 + i] = run; run += local[i]; }
    // bucket bases: flat index k*NSCB = 512k = 16*t -> t = 32k
    if ((t & 31) == 0) bases[t >> 5] = ex;
    if (t == 0) bases[NBUCKET] = N;
}

// ---------- pass 2c: scatter records into packed bucket regions ----------
__global__ __launch_bounds__(256) void scatter_kernel(
        const float* __restrict__ grid,
        const int* __restrict__ offs,
        uint4v* __restrict__ recs) {
    __shared__ int lcur[NBUCKET];
    if (threadIdx.x < NBUCKET)
        lcur[threadIdx.x] = offs[threadIdx.x * NSCB + blockIdx.x];
    __syncthreads();

    const int nb = blockIdx.x * SPB;
    const int lane = threadIdx.x & 63;
    for (int s = 0; s < ITER; ++s) {
        const int n = nb + s * 256 + threadIdx.x;
        const float gx = __builtin_nontemporal_load(&grid[3 * n + 0]);
        const float gy = __builtin_nontemporal_load(&grid[3 * n + 1]);
        const float gz = __builtin_nontemporal_load(&grid[3 * n + 2]);

        const float fx = floorf(gx), fy = floorf(gy), fz = floorf(gz);
        const int lx = (int)fx, ly = (int)fy, lz = (int)fz;
        const float tx = gx - fx, ty = gy - fy, tz = gz - fz;

        const int ix0 = reflect_dct2(lx,     DIM);
        const int ix1 = reflect_dct2(lx + 1, DIM);
        const int iy0 = reflect_dct2(ly,     DIM);
        const int iy1 = reflect_dct2(ly + 1, DIM);
        const int iz0 = reflect_dct2(lz,     DIM);
        const int iz1 = reflect_dct2(lz + 1, DIM);

        const int b = ix0 / 24;

        const uint32_t u1 = (uint32_t)ix0 | ((uint32_t)iy0 << 8) | ((uint32_t)iz0 << 16)
                          | ((uint32_t)(ix1 - ix0 + 1) << 24)
                          | ((uint32_t)(iy1 - iy0 + 1) << 26)
                          | ((uint32_t)(iz1 - iz0 + 1) << 28);
        const uint32_t txq = (uint32_t)(tx * 65536.0f);
        const uint32_t tyq = (uint32_t)(ty * 65536.0f);
        const uint32_t tzq = (uint32_t)(tz * 65536.0f);
        const uint4v rec = { (uint32_t)n, u1, txq | (tyq << 16), tzq };

        int pos = 0;
#pragma unroll
        for (int k = 0; k < NBUCKET; ++k) {
            const unsigned long long m = __ballot(b == k);
            if (m) {
                const int leader = __ffsll((long long)m) - 1;
                int bse = 0;
                if (lane == leader) bse = atomicAdd(&lcur[k], __popcll(m));  // LDS only
                bse = __shfl(bse, leader);
                if (b == k) pos = bse + __popcll(m & ((1ull << lane) - 1ull));
            }
        }
        __builtin_nontemporal_store(rec, &recs[pos]);
    }
}

// ---------- pass 3: process buckets (XCD-affine via blockIdx%8) ----------
__global__ __launch_bounds__(256) void process_kernel(
        const uint32_t* __restrict__ xb,
        const uint4v* __restrict__ recs,
        const int* __restrict__ bases,
        float* __restrict__ out) {
    const int region = blockIdx.x & 7;               // round-robin -> XCD affinity
    const int chunk  = blockIdx.x >> 3;
    const int idx = chunk * 256 + threadIdx.x;
    const int base = bases[region];
    const int cnt  = bases[region + 1] - base;
    if (idx >= cnt) return;

    const uint4v r = __builtin_nontemporal_load(&recs[(size_t)base + idx]);
    const int n = (int)r.x;
    const int ix0 = r.y & 255, iy0 = (r.y >> 8) & 255, iz0 = (r.y >> 16) & 255;
    const int ix1 = ix0 + (int)((r.y >> 24) & 3) - 1;
    const int iy1 = iy0 + (int)((r.y >> 26) & 3) - 1;
    const int iz1 = iz0 + (int)((r.y >> 28) & 3) - 1;
    const float tx = (float)(r.z & 65535u) * (1.0f / 65536.0f);
    const float ty = (float)(r.z >> 16)    * (1.0f / 65536.0f);
    const float tz = (float)(r.w & 65535u) * (1.0f / 65536.0f);

    const int tx0 = xterm(ix0), tx1 = xterm(ix1);
    const int ty0 = yterm(iy0), ty1 = yterm(iy1);
    const int tz0 = zterm(iz0), tz1 = zterm(iz1);

    const uint32_t u000 = xb[tx0 + ty0 + tz0];
    const uint32_t u001 = xb[tx0 + ty0 + tz1];
    const uint32_t u010 = xb[tx0 + ty1 + tz0];
    const uint32_t u011 = xb[tx0 + ty1 + tz1];
    const uint32_t u100 = xb[tx1 + ty0 + tz0];
    const uint32_t u101 = xb[tx1 + ty0 + tz1];
    const uint32_t u110 = xb[tx1 + ty1 + tz0];
    const uint32_t u111 = xb[tx1 + ty1 + tz1];

    const float wx0 = 1.0f - tx, wx1 = tx;
    const float wy0 = 1.0f - ty, wy1 = ty;
    const float wz0 = 1.0f - tz, wz1 = tz;

    const float w000 = wx0 * wy0 * wz0, w001 = wx0 * wy0 * wz1;
    const float w010 = wx0 * wy1 * wz0, w011 = wx0 * wy1 * wz1;
    const float w100 = wx1 * wy0 * wz0, w101 = wx1 * wy0 * wz1;
    const float w110 = wx1 * wy1 * wz0, w111 = wx1 * wy1 * wz1;

    const float2 f000 = __half22float2(__builtin_bit_cast(__half2, u000));
    const float2 f001 = __half22float2(__builtin_bit_cast(__half2, u001));
    const float2 f010 = __half22float2(__builtin_bit_cast(__half2, u010));
    const float2 f011 = __half22float2(__builtin_bit_cast(__half2, u011));
    const float2 f100 = __half22float2(__builtin_bit_cast(__half2, u100));
    const float2 f101 = __half22float2(__builtin_bit_cast(__half2, u101));
    const float2 f110 = __half22float2(__builtin_bit_cast(__half2, u110));
    const float2 f111 = __half22float2(__builtin_bit_cast(__half2, u111));

    const float acc0 = f000.x * w000 + f001.x * w001 + f010.x * w010 + f011.x * w011
                     + f100.x * w100 + f101.x * w101 + f110.x * w110 + f111.x * w111;
    const float acc1 = f000.y * w000 + f001.y * w001 + f010.y * w010 + f011.y * w011
                     + f100.y * w100 + f101.y * w101 + f110.y * w110 + f111.y * w111;

    out[n]     = acc0;     // plain stores: want L2 write-merging
    out[N + n] = acc1;
}

// ---------- fallback: R3 monolithic brick gather ----------
__global__ __launch_bounds__(256) void grid_pull_brick_kernel(
        const uint32_t* __restrict__ xb,
        const float* __restrict__ grid,
        float* __restrict__ out) {
    const int n = blockIdx.x * blockDim.x + threadIdx.x;
    if (n >= N) return;

    const float gx = __builtin_nontemporal_load(&grid[3 * n + 0]);
    const float gy = __builtin_nontemporal_load(&grid[3 * n + 1]);
    const float gz = __builtin_nontemporal_load(&grid[3 * n + 2]);

    const float fx = floorf(gx), fy = floorf(gy), fz = floorf(gz);
    const int lx = (int)fx, ly = (int)fy, lz = (int)fz;
    const float tx = gx - fx, ty = gy - fy, tz = gz - fz;

    const int ix0 = reflect_dct2(lx,     DIM);
    const int ix1 = reflect_dct2(lx + 1, DIM);
    const int iy0 = reflect_dct2(ly,     DIM);
    const int iy1 = reflect_dct2(ly + 1, DIM);
    const int iz0 = reflect_dct2(lz,     DIM);
    const int iz1 = reflect_dct2(lz + 1, DIM);

    const int tx0 = xterm(ix0), tx1 = xterm(ix1);
    const int ty0 = yterm(iy0), ty1 = yterm(iy1);
    const int tz0 = zterm(iz0), tz1 = zterm(iz1);

    const uint32_t u000 = xb[tx0 + ty0 + tz0];
    const uint32_t u001 = xb[tx0 + ty0 + tz1];
    const uint32_t u010 = xb[tx0 + ty1 + tz0];
    const uint32_t u011 = xb[tx0 + ty1 + tz1];
    const uint32_t u100 = xb[tx1 + ty0 + tz0];
    const uint32_t u101 = xb[tx1 + ty0 + tz1];
    const uint32_t u110 = xb[tx1 + ty1 + tz0];
    const uint32_t u111 = xb[tx1 + ty1 + tz1];

    const float wx0 = 1.0f - tx, wx1 = tx;
    const float wy0 = 1.0f - ty, wy1 = ty;
    const float wz0 = 1.0f - tz, wz1 = tz;

    const float w000 = wx0 * wy0 * wz0, w001 = wx0 * wy0 * wz1;
    const float w010 = wx0 * wy1 * wz0, w011 = wx0 * wy1 * wz1;
    const float w100 = wx1 * wy0 * wz0, w101 = wx1 * wy0 * wz1;
    const float w110 = wx1 * wy1 * wz0, w111 = wx1 * wy1 * wz1;

    const float2 f000 = __half22float2(__builtin_bit_cast(__half2, u000));
    const float2 f001 = __half22float2(__builtin_bit_cast(__half2, u001));
    const float2 f010 = __half22float2(__builtin_bit_cast(__half2, u010));
    const float2 f011 = __half22float2(__builtin_bit_cast(__half2, u011));
    const float2 f100 = __half22float2(__builtin_bit_cast(__half2, u100));
    const float2 f101 = __half22float2(__builtin_bit_cast(__half2, u101));
    const float2 f110 = __half22float2(__builtin_bit_cast(__half2, u110));
    const float2 f111 = __half22float2(__builtin_bit_cast(__half2, u111));

    const float acc0 = f000.x * w000 + f001.x * w001 + f010.x * w010 + f011.x * w011
                     + f100.x * w100 + f101.x * w101 + f110.x * w110 + f111.x * w111;
    const float acc1 = f000.y * w000 + f001.y * w001 + f010.y * w010 + f011.y * w011
                     + f100.y * w100 + f101.y * w101 + f110.y * w110 + f111.y * w111;

    __builtin_nontemporal_store(acc0, &out[n]);
    __builtin_nontemporal_store(acc1, &out[N + n]);
}

extern "C" void kernel_launch(void* const* d_in, const int* in_sizes, int n_in,
                              void* d_out, int out_size, void* d_ws, size_t ws_size,
                              hipStream_t stream) {
    const float* x    = (const float*)d_in[0];
    const float* grid = (const float*)d_in[1];
    float* out        = (float*)d_out;

    const int threads = 256;
    const int rblocks = (NBRICKS + threads - 1) / threads;
    const int gblocks = N / threads;                 // exact

    if (ws_size >= WS_NEED) {
        uint32_t* xb  = (uint32_t*)d_ws;
        uint4v* recs  = (uint4v*)((char*)d_ws + BRICK_BYTES);
        int* hist     = (int*)((char*)d_ws + HIST_OFF);
        int* offs     = (int*)((char*)d_ws + OFFS_OFF);
        int* bases    = (int*)((char*)d_ws + BASE_OFF);

        repack_brick_kernel<<<rblocks, threads, 0, stream>>>(x, xb);
        count_kernel<<<NSCB, threads, 0, stream>>>(grid, hist);
        scan_kernel<<<1, threads, 0, stream>>>(hist, offs, bases);
        scatter_kernel<<<NSCB, threads, 0, stream>>>(grid, offs, recs);
        process_kernel<<<NBUCKET * PB_BLOCKS, threads, 0, stream>>>(xb, recs, bases, out);
    } else {
        // fallback: R3 path (needs 28.3 MB)
        uint32_t* xb = (uint32_t*)d_ws;
        repack_brick_kernel<<<rblocks, threads, 0, stream>>>(x, xb);
        grid_pull_brick_kernel<<<gblocks, threads, 0, stream>>>(xb, grid, out);
    }
}

// Round 7
// 531.956 us; speedup vs baseline: 19.7578x; 1.1663x over previous
//
#include <hip/hip_runtime.h>
#include <hip/hip_fp16.h>

// GridPull: trilinear interpolation, dct2 reflect boundary, extrapolate=True.
// x: (1, 2, 192, 192, 192) f32; grid: (1, 192, 192, 192, 3) f32 -> (1, 2, 192^3) f32.
//
// R7: bucketed gather with XCD-local writes.
//   R6 proved blockIdx%8 XCD affinity slashes gather misses (823->~100 MB) but
//   scatter-writing `out` from 8 XCDs caused 5x write amplification (each out
//   line owned by ~7 buckets). Fix: process writes results IN PLACE into its
//   own 12B record slot (block-private segments, no cross-XCD lines); a final
//   unpermute pass reads inv[n] (coalesced) + rec[inv[n]] (8 interleaved
//   sequential streams -> near-full lines) and writes out coalesced.
// Pipeline: repack -> count -> scan -> scatter(+inv) -> process -> unpermute.

constexpr int DIM = 192;
constexpr int N = DIM * DIM * DIM;           // 7,077,888

// brick geometry: 4(x) x 2(y) x 2(z) voxels * half2 = one 64 B line
constexpr int NBX = DIM / 4, NBY = DIM / 2, NBZ = DIM / 2;
constexpr int NBRICKS = NBX * NBY * NBZ;
constexpr int XSTRIDE = NBY * NBZ * 16;      // half2 units per +4 in ix
constexpr int YSTRIDE = NBZ * 16;            // per +2 in iy
constexpr int ZSTRIDE = 16;                  // per +2 in iz

constexpr int NBUCKET = 8;                   // x-slabs of 24 planes
constexpr int NSCB = 512;                    // count/scatter blocks
constexpr int SPB  = N / NSCB;               // 13824 samples per block
constexpr int ITER = SPB / 256;              // 54
constexpr int HIST_N = NBUCKET * NSCB;       // 4096
constexpr int PB_BLOCKS = 3840;              // process blocks per bucket (covers 983040 >= max bucket ~944K)

constexpr size_t BRICK_BYTES = (size_t)NBRICKS * 64;   // 28,311,552
constexpr size_t REC_BYTES   = (size_t)N * 12;         // 84,934,656 (12 B records)
constexpr size_t INV_OFF     = BRICK_BYTES + REC_BYTES;
constexpr size_t HIST_OFF    = INV_OFF + (size_t)N * 4;
constexpr size_t OFFS_OFF    = HIST_OFF + (size_t)HIST_N * 4;
constexpr size_t BASE_OFF    = OFFS_OFF + (size_t)HIST_N * 4;
constexpr size_t WS_NEED     = BASE_OFF + 64;          // ~141.6 MB (== R6 footprint, proven granted)

// nontemporal-legal 16B vector type (HIP's uint4 is a class -> rejected)
typedef unsigned int uint4v __attribute__((ext_vector_type(4)));

__device__ __forceinline__ int reflect_dct2(int i, int n) {
    const int p = 2 * n;
    i = ((i % p) + p) % p;
    return (i >= n) ? (p - 1 - i) : i;
}

__device__ __forceinline__ int xterm(int ix) { return (ix >> 2) * XSTRIDE + ((ix & 3) << 2); }
__device__ __forceinline__ int yterm(int iy) { return (iy >> 1) * YSTRIDE + ((iy & 1) << 1); }
__device__ __forceinline__ int zterm(int iz) { return (iz >> 1) * ZSTRIDE + (iz & 1); }

// ---------- pass 1: fp16 brick repack ----------
__global__ __launch_bounds__(256) void repack_brick_kernel(
        const float* __restrict__ x, uint32_t* __restrict__ xb) {
    const int b = blockIdx.x * blockDim.x + threadIdx.x;
    if (b >= NBRICKS) return;
    const int bz = b % NBZ;
    const int t  = b / NBZ;
    const int by = t % NBY;
    const int bx = t / NBY;
    const int ix0 = bx * 4, iy0 = by * 2, iz0 = bz * 2;

    uint32_t vals[16];
#pragma unroll
    for (int s = 0; s < 16; ++s) {
        const int ix = ix0 + (s >> 2);
        const int iy = iy0 + ((s >> 1) & 1);
        const int iz = iz0 + (s & 1);
        const int n = (ix * DIM + iy) * DIM + iz;
        const __half2 h = __floats2half2_rn(x[n], x[N + n]);
        vals[s] = __builtin_bit_cast(uint32_t, h);
    }
    uint4v* dst = (uint4v*)(xb + (size_t)b * 16);
#pragma unroll
    for (int q = 0; q < 4; ++q) {
        uint4v v = { vals[4 * q + 0], vals[4 * q + 1], vals[4 * q + 2], vals[4 * q + 3] };
        dst[q] = v;
    }
}

// ---------- pass 2a: per-block bucket histograms (no global atomics) ----------
__global__ __launch_bounds__(256) void count_kernel(
        const float* __restrict__ grid, int* __restrict__ hist) {
    __shared__ int lh[NBUCKET];
    if (threadIdx.x < NBUCKET) lh[threadIdx.x] = 0;
    __syncthreads();

    int acc[NBUCKET];
#pragma unroll
    for (int k = 0; k < NBUCKET; ++k) acc[k] = 0;

    const int base = blockIdx.x * SPB;
    for (int s = 0; s < ITER; ++s) {
        const int n = base + s * 256 + threadIdx.x;
        const float gx = __builtin_nontemporal_load(&grid[3 * n]);
        const int ix0 = reflect_dct2((int)floorf(gx), DIM);
        const int b = ix0 / 24;
#pragma unroll
        for (int k = 0; k < NBUCKET; ++k) {
            const unsigned long long m = __ballot(b == k);
            acc[k] += __popcll(m);          // wave-uniform
        }
    }
    const int lane = threadIdx.x & 63;
#pragma unroll
    for (int k = 0; k < NBUCKET; ++k)
        if (lane == k) atomicAdd(&lh[k], acc[k]);   // LDS, 8 per wave total
    __syncthreads();
    if (threadIdx.x < NBUCKET)
        hist[threadIdx.x * NSCB + blockIdx.x] = lh[threadIdx.x];
}

// ---------- pass 2b: exclusive scan of 4096 hist entries (1 block) ----------
__global__ __launch_bounds__(256) void scan_kernel(
        const int* __restrict__ hist, int* __restrict__ offs, int* __restrict__ bases) {
    __shared__ int ls[256];
    const int t = threadIdx.x;
    int local[16];
    int sum = 0;
#pragma unroll
    for (int i = 0; i < 16; ++i) { local[i] = hist[t * 16 + i]; sum += local[i]; }
    ls[t] = sum;
    __syncthreads();
    for (int off = 1; off < 256; off <<= 1) {
        int v = 0;
        if (t >= off) v = ls[t - off];
        __syncthreads();
        ls[t] += v;
        __syncthreads();
    }
    const int ex = ls[t] - sum;              // exclusive prefix at flat index 16*t
    int run = ex;
#pragma unroll
    for (int i = 0; i < 16; ++i) { offs[t * 16 + i] = run; run += local[i]; }
    // bucket bases: flat index k*NSCB = 512k = 16*t -> t = 32k
    if ((t & 31) == 0) bases[t >> 5] = ex;
    if (t == 0) bases[NBUCKET] = N;
}

// ---------- pass 2c: scatter 12B records + inverse permutation ----------
__global__ __launch_bounds__(256) void scatter_kernel(
        const float* __restrict__ grid,
        const int* __restrict__ offs,
        uint32_t* __restrict__ recs,        // 12 B slots: 3 dwords each
        uint32_t* __restrict__ inv) {
    __shared__ int lcur[NBUCKET];
    if (threadIdx.x < NBUCKET)
        lcur[threadIdx.x] = offs[threadIdx.x * NSCB + blockIdx.x];
    __syncthreads();

    const int nb = blockIdx.x * SPB;
    const int lane = threadIdx.x & 63;
    for (int s = 0; s < ITER; ++s) {
        const int n = nb + s * 256 + threadIdx.x;
        const float gx = __builtin_nontemporal_load(&grid[3 * n + 0]);
        const float gy = __builtin_nontemporal_load(&grid[3 * n + 1]);
        const float gz = __builtin_nontemporal_load(&grid[3 * n + 2]);

        const float fx = floorf(gx), fy = floorf(gy), fz = floorf(gz);
        const int lx = (int)fx, ly = (int)fy, lz = (int)fz;
        const float tx = gx - fx, ty = gy - fy, tz = gz - fz;

        const int ix0 = reflect_dct2(lx,     DIM);
        const int ix1 = reflect_dct2(lx + 1, DIM);
        const int iy0 = reflect_dct2(ly,     DIM);
        const int iy1 = reflect_dct2(ly + 1, DIM);
        const int iz0 = reflect_dct2(lz,     DIM);
        const int iz1 = reflect_dct2(lz + 1, DIM);

        const int b = ix0 / 24;

        const uint32_t d0 = (uint32_t)ix0 | ((uint32_t)iy0 << 8) | ((uint32_t)iz0 << 16)
                          | ((uint32_t)(ix1 - ix0 + 1) << 24)
                          | ((uint32_t)(iy1 - iy0 + 1) << 26)
                          | ((uint32_t)(iz1 - iz0 + 1) << 28);
        const uint32_t txq = (uint32_t)(tx * 65536.0f);
        const uint32_t tyq = (uint32_t)(ty * 65536.0f);
        const uint32_t tzq = (uint32_t)(tz * 65536.0f);

        int pos = 0;
#pragma unroll
        for (int k = 0; k < NBUCKET; ++k) {
            const unsigned long long m = __ballot(b == k);
            if (m) {
                const int leader = __ffsll((long long)m) - 1;
                int bse = 0;
                if (lane == leader) bse = atomicAdd(&lcur[k], __popcll(m));  // LDS only
                bse = __shfl(bse, leader);
                if (b == k) pos = bse + __popcll(m & ((1ull << lane) - 1ull));
            }
        }
        uint32_t* rp = recs + (size_t)pos * 3;
        rp[0] = d0;
        rp[1] = txq | (tyq << 16);
        rp[2] = tzq;
        __builtin_nontemporal_store((uint32_t)pos, &inv[n]);
    }
}

// ---------- pass 3: process buckets (XCD-affine), result in place ----------
__global__ __launch_bounds__(256) void process_kernel(
        const uint32_t* __restrict__ xb,
        uint32_t* __restrict__ recs,
        const int* __restrict__ bases) {
    const int region = blockIdx.x & 7;               // round-robin -> XCD affinity
    const int chunk  = blockIdx.x >> 3;
    const int idx = chunk * 256 + threadIdx.x;
    const int base = bases[region];
    const int cnt  = bases[region + 1] - base;
    if (idx >= cnt) return;
    const int pos = base + idx;

    uint32_t* rp = recs + (size_t)pos * 3;
    const uint32_t d0 = rp[0];
    const uint32_t d1 = rp[1];
    const uint32_t d2 = rp[2];

    const int ix0 = d0 & 255, iy0 = (d0 >> 8) & 255, iz0 = (d0 >> 16) & 255;
    const int ix1 = ix0 + (int)((d0 >> 24) & 3) - 1;
    const int iy1 = iy0 + (int)((d0 >> 26) & 3) - 1;
    const int iz1 = iz0 + (int)((d0 >> 28) & 3) - 1;
    const float tx = (float)(d1 & 65535u) * (1.0f / 65536.0f);
    const float ty = (float)(d1 >> 16)    * (1.0f / 65536.0f);
    const float tz = (float)(d2 & 65535u) * (1.0f / 65536.0f);

    const int tx0 = xterm(ix0), tx1 = xterm(ix1);
    const int ty0 = yterm(iy0), ty1 = yterm(iy1);
    const int tz0 = zterm(iz0), tz1 = zterm(iz1);

    const uint32_t u000 = xb[tx0 + ty0 + tz0];
    const uint32_t u001 = xb[tx0 + ty0 + tz1];
    const uint32_t u010 = xb[tx0 + ty1 + tz0];
    const uint32_t u011 = xb[tx0 + ty1 + tz1];
    const uint32_t u100 = xb[tx1 + ty0 + tz0];
    const uint32_t u101 = xb[tx1 + ty0 + tz1];
    const uint32_t u110 = xb[tx1 + ty1 + tz0];
    const uint32_t u111 = xb[tx1 + ty1 + tz1];

    const float wx0 = 1.0f - tx, wx1 = tx;
    const float wy0 = 1.0f - ty, wy1 = ty;
    const float wz0 = 1.0f - tz, wz1 = tz;

    const float w000 = wx0 * wy0 * wz0, w001 = wx0 * wy0 * wz1;
    const float w010 = wx0 * wy1 * wz0, w011 = wx0 * wy1 * wz1;
    const float w100 = wx1 * wy0 * wz0, w101 = wx1 * wy0 * wz1;
    const float w110 = wx1 * wy1 * wz0, w111 = wx1 * wy1 * wz1;

    const float2 f000 = __half22float2(__builtin_bit_cast(__half2, u000));
    const float2 f001 = __half22float2(__builtin_bit_cast(__half2, u001));
    const float2 f010 = __half22float2(__builtin_bit_cast(__half2, u010));
    const float2 f011 = __half22float2(__builtin_bit_cast(__half2, u011));
    const float2 f100 = __half22float2(__builtin_bit_cast(__half2, u100));
    const float2 f101 = __half22float2(__builtin_bit_cast(__half2, u101));
    const float2 f110 = __half22float2(__builtin_bit_cast(__half2, u110));
    const float2 f111 = __half22float2(__builtin_bit_cast(__half2, u111));

    const float acc0 = f000.x * w000 + f001.x * w001 + f010.x * w010 + f011.x * w011
                     + f100.x * w100 + f101.x * w101 + f110.x * w110 + f111.x * w111;
    const float acc1 = f000.y * w000 + f001.y * w001 + f010.y * w010 + f011.y * w011
                     + f100.y * w100 + f101.y * w101 + f110.y * w110 + f111.y * w111;

    // in-place result: same thread, same 12B slot -> race-free; block-private
    // segments -> no cross-XCD partial-line writes.
    rp[0] = __builtin_bit_cast(uint32_t, acc0);
    rp[1] = __builtin_bit_cast(uint32_t, acc1);
}

// ---------- pass 4: unpermute (coalesced out writes) ----------
__global__ __launch_bounds__(256) void unpermute_kernel(
        const uint32_t* __restrict__ recs,
        const uint32_t* __restrict__ inv,
        float* __restrict__ out) {
    const int n = blockIdx.x * 256 + threadIdx.x;
    const uint32_t pos = __builtin_nontemporal_load(&inv[n]);
    const uint32_t* rp = recs + (size_t)pos * 3;
    const float f0 = __builtin_bit_cast(float, rp[0]);
    const float f1 = __builtin_bit_cast(float, rp[1]);
    __builtin_nontemporal_store(f0, &out[n]);
    __builtin_nontemporal_store(f1, &out[N + n]);
}

// ---------- fallback: R3 monolithic brick gather ----------
__global__ __launch_bounds__(256) void grid_pull_brick_kernel(
        const uint32_t* __restrict__ xb,
        const float* __restrict__ grid,
        float* __restrict__ out) {
    const int n = blockIdx.x * blockDim.x + threadIdx.x;
    if (n >= N) return;

    const float gx = __builtin_nontemporal_load(&grid[3 * n + 0]);
    const float gy = __builtin_nontemporal_load(&grid[3 * n + 1]);
    const float gz = __builtin_nontemporal_load(&grid[3 * n + 2]);

    const float fx = floorf(gx), fy = floorf(gy), fz = floorf(gz);
    const int lx = (int)fx, ly = (int)fy, lz = (int)fz;
    const float tx = gx - fx, ty = gy - fy, tz = gz - fz;

    const int ix0 = reflect_dct2(lx,     DIM);
    const int ix1 = reflect_dct2(lx + 1, DIM);
    const int iy0 = reflect_dct2(ly,     DIM);
    const int iy1 = reflect_dct2(ly + 1, DIM);
    const int iz0 = reflect_dct2(lz,     DIM);
    const int iz1 = reflect_dct2(lz + 1, DIM);

    const int tx0 = xterm(ix0), tx1 = xterm(ix1);
    const int ty0 = yterm(iy0), ty1 = yterm(iy1);
    const int tz0 = zterm(iz0), tz1 = zterm(iz1);

    const uint32_t u000 = xb[tx0 + ty0 + tz0];
    const uint32_t u001 = xb[tx0 + ty0 + tz1];
    const uint32_t u010 = xb[tx0 + ty1 + tz0];
    const uint32_t u011 = xb[tx0 + ty1 + tz1];
    const uint32_t u100 = xb[tx1 + ty0 + tz0];
    const uint32_t u101 = xb[tx1 + ty0 + tz1];
    const uint32_t u110 = xb[tx1 + ty1 + tz0];
    const uint32_t u111 = xb[tx1 + ty1 + tz1];

    const float wx0 = 1.0f - tx, wx1 = tx;
    const float wy0 = 1.0f - ty, wy1 = ty;
    const float wz0 = 1.0f - tz, wz1 = tz;

    const float w000 = wx0 * wy0 * wz0, w001 = wx0 * wy0 * wz1;
    const float w010 = wx0 * wy1 * wz0, w011 = wx0 * wy1 * wz1;
    const float w100 = wx1 * wy0 * wz0, w101 = wx1 * wy0 * wz1;
    const float w110 = wx1 * wy1 * wz0, w111 = wx1 * wy1 * wz1;

    const float2 f000 = __half22float2(__builtin_bit_cast(__half2, u000));
    const float2 f001 = __half22float2(__builtin_bit_cast(__half2, u001));
    const float2 f010 = __half22float2(__builtin_bit_cast(__half2, u010));
    const float2 f011 = __half22float2(__builtin_bit_cast(__half2, u011));
    const float2 f100 = __half22float2(__builtin_bit_cast(__half2, u100));
    const float2 f101 = __half22float2(__builtin_bit_cast(__half2, u101));
    const float2 f110 = __half22float2(__builtin_bit_cast(__half2, u110));
    const float2 f111 = __half22float2(__builtin_bit_cast(__half2, u111));

    const float acc0 = f000.x * w000 + f001.x * w001 + f010.x * w010 + f011.x * w011
                     + f100.x * w100 + f101.x * w101 + f110.x * w110 + f111.x * w111;
    const float acc1 = f000.y * w000 + f001.y * w001 + f010.y * w010 + f011.y * w011
                     + f100.y * w100 + f101.y * w101 + f110.y * w110 + f111.y * w111;

    __builtin_nontemporal_store(acc0, &out[n]);
    __builtin_nontemporal_store(acc1, &out[N + n]);
}

extern "C" void kernel_launch(void* const* d_in, const int* in_sizes, int n_in,
                              void* d_out, int out_size, void* d_ws, size_t ws_size,
                              hipStream_t stream) {
    const float* x    = (const float*)d_in[0];
    const float* grid = (const float*)d_in[1];
    float* out        = (float*)d_out;

    const int threads = 256;
    const int rblocks = (NBRICKS + threads - 1) / threads;
    const int gblocks = N / threads;                 // exact

    if (ws_size >= WS_NEED) {
        uint32_t* xb  = (uint32_t*)d_ws;
        uint32_t* recs = (uint32_t*)((char*)d_ws + BRICK_BYTES);
        uint32_t* inv  = (uint32_t*)((char*)d_ws + INV_OFF);
        int* hist      = (int*)((char*)d_ws + HIST_OFF);
        int* offs      = (int*)((char*)d_ws + OFFS_OFF);
        int* bases     = (int*)((char*)d_ws + BASE_OFF);

        repack_brick_kernel<<<rblocks, threads, 0, stream>>>(x, xb);
        count_kernel<<<NSCB, threads, 0, stream>>>(grid, hist);
        scan_kernel<<<1, threads, 0, stream>>>(hist, offs, bases);
        scatter_kernel<<<NSCB, threads, 0, stream>>>(grid, offs, recs, inv);
        process_kernel<<<NBUCKET * PB_BLOCKS, threads, 0, stream>>>(xb, recs, bases);
        unpermute_kernel<<<gblocks, threads, 0, stream>>>(recs, inv, out);
    } else {
        // fallback: R3 path (needs 28.3 MB)
        uint32_t* xb = (uint32_t*)d_ws;
        repack_brick_kernel<<<rblocks, threads, 0, stream>>>(x, xb);
        grid_pull_brick_kernel<<<gblocks, threads, 0, stream>>>(xb, grid, out);
    }
}